// Round 8
// baseline (6643.285 us; speedup 1.0000x reference)
//
#include <hip/hip_runtime.h>
#include <math.h>

// B=16, S=128, H=512, V=50000, N=5, R=2, Wd=512, XI=2573
#define EPSC 1e-6f
#define NBLK 128

// ws layout (float offsets)
#define OFF_H     0u         // hbuf[2][16][512]
#define OFF_R     16384u     // r[16][1024]
#define OFF_FLAGS 32768u     // arrival flags: 128 x 32 u32
#define OFF_GO    36864u     // (unused, kept for layout)
#define STATE_END 40960u
#define OFF_XI    40960u     // xi[16][3072] (padded rows)
#define OFF_GX    90112u     // gates_x[128][16][2048]
#define OFF_HR    4284416u   // hr[128][16][1536]
// end 7430144 floats = 29.7 MB

typedef float f32x4 __attribute__((ext_vector_type(4)));

__device__ __forceinline__ float sigmf(float x) { return 1.0f / (1.0f + expf(-x)); }
__device__ __forceinline__ float oneplusf(float x) {
    return 1.0f + fmaxf(x, 0.0f) + log1pf(expf(-fabsf(x)));
}

// coherent scalar store (agent scope, bypasses L1/L2) — proven r3-r7
__device__ __forceinline__ void gst(float* p, float v) {
    __hip_atomic_store((unsigned*)p, __float_as_uint(v),
                       __ATOMIC_RELAXED, __HIP_MEMORY_SCOPE_AGENT);
}

// 12 coherent dwordx4 loads, 2 base ptrs + offset immediates, one waitcnt.
__device__ __forceinline__ void stage12(
    f32x4& d0, f32x4& d1, f32x4& d2, f32x4& d3, f32x4& d4, f32x4& d5,
    f32x4& d6, f32x4& d7, f32x4& d8, f32x4& d9, f32x4& d10, f32x4& d11,
    const float* ph, const float* pr)
{
    asm volatile(
        "global_load_dwordx4 %0, %12, off sc0 sc1\n\t"
        "global_load_dwordx4 %1, %12, off offset:512 sc0 sc1\n\t"
        "global_load_dwordx4 %2, %12, off offset:1024 sc0 sc1\n\t"
        "global_load_dwordx4 %3, %12, off offset:1536 sc0 sc1\n\t"
        "global_load_dwordx4 %4, %13, off sc0 sc1\n\t"
        "global_load_dwordx4 %5, %13, off offset:512 sc0 sc1\n\t"
        "global_load_dwordx4 %6, %13, off offset:1024 sc0 sc1\n\t"
        "global_load_dwordx4 %7, %13, off offset:1536 sc0 sc1\n\t"
        "global_load_dwordx4 %8, %13, off offset:2048 sc0 sc1\n\t"
        "global_load_dwordx4 %9, %13, off offset:2560 sc0 sc1\n\t"
        "global_load_dwordx4 %10, %13, off offset:3072 sc0 sc1\n\t"
        "global_load_dwordx4 %11, %13, off offset:3584 sc0 sc1\n\t"
        "s_waitcnt vmcnt(0)"
        : "=&v"(d0), "=&v"(d1), "=&v"(d2), "=&v"(d3), "=&v"(d4), "=&v"(d5),
          "=&v"(d6), "=&v"(d7), "=&v"(d8), "=&v"(d9), "=&v"(d10), "=&v"(d11)
        : "v"(ph), "v"(pr)
        : "memory");
}

// 4 coherent dwordx4 loads from one base, offsets 0/512/1024/1536.
__device__ __forceinline__ void cld4o(
    f32x4& d0, f32x4& d1, f32x4& d2, f32x4& d3, const float* p)
{
    asm volatile(
        "global_load_dwordx4 %0, %4, off sc0 sc1\n\t"
        "global_load_dwordx4 %1, %4, off offset:512 sc0 sc1\n\t"
        "global_load_dwordx4 %2, %4, off offset:1024 sc0 sc1\n\t"
        "global_load_dwordx4 %3, %4, off offset:1536 sc0 sc1\n\t"
        "s_waitcnt vmcnt(0)"
        : "=&v"(d0), "=&v"(d1), "=&v"(d2), "=&v"(d3)
        : "v"(p)
        : "memory");
}

__device__ __forceinline__ void cld2(
    f32x4& d0, f32x4& d1, const float* p, const float* q)
{
    asm volatile(
        "global_load_dwordx4 %0, %2, off sc0 sc1\n\t"
        "global_load_dwordx4 %1, %3, off sc0 sc1\n\t"
        "s_waitcnt vmcnt(0)"
        : "=&v"(d0), "=&v"(d1)
        : "v"(p), "v"(q)
        : "memory");
}

// Fence-free 1-hop grid barrier: each block stores its own flag line;
// every block's lanes 0..127 poll all 128 flag lines directly.
__device__ __forceinline__ void gsync(unsigned* flags, unsigned gen,
                                      int bi, int tid)
{
    __builtin_amdgcn_s_waitcnt(0);   // drain this wave's payload stores
    __syncthreads();
    if (tid == 0)
        __hip_atomic_store(&flags[bi * 32], gen, __ATOMIC_RELAXED, __HIP_MEMORY_SCOPE_AGENT);
    if (tid < NBLK) {
        unsigned v;
        do {
            v = __hip_atomic_load(&flags[tid * 32], __ATOMIC_RELAXED, __HIP_MEMORY_SCOPE_AGENT);
            if (v < gen) __builtin_amdgcn_s_sleep(2);
        } while (v < gen);
    }
    __syncthreads();
}

template <int K>
__device__ __forceinline__ void blk_reduce(float* v, float (*s_red)[20],
                                           float* outp, int tid)
{
#pragma unroll
    for (int i = 0; i < K; i++) {
        float x = v[i];
        for (int o = 32; o > 0; o >>= 1) x += __shfl_down(x, o, 64);
        if ((tid & 63) == 0) s_red[tid >> 6][i] = x;
    }
    __syncthreads();
    if (tid < K) {
        float s = 0.f;
#pragma unroll
        for (int w = 0; w < 8; w++) s += s_red[w][tid];
        outp[tid] = s;
    }
    __syncthreads();
}

// ---------------------------------------------------------------------------
// Persistent kernel: all 128 DNC steps. 128 blocks x 512 threads.
// ---------------------------------------------------------------------------
__global__ __launch_bounds__(512, 1) void k_main(
    const float* __restrict__ W_ih, const float* __restrict__ W_hh,
    const float* __restrict__ W_int, const float* __restrict__ b_int,
    const float* __restrict__ gx, float* __restrict__ hbuf,
    float* __restrict__ rbuf, float* __restrict__ xib,
    float* __restrict__ hr, float* __restrict__ out,
    unsigned* __restrict__ flags)
{
    const int tid = threadIdx.x;
    const int bi  = blockIdx.x;

    // ---- LDS (~125 KB) ----
    __shared__ __align__(16) float big_u[26624];  // G: 16 rows x 1664 (chunk-52)
    __shared__ float s_part[2048];
    __shared__ float s_tot[256];
    __shared__ float c_s[64];                     // persistent c (4 j x 16 b)
    __shared__ __align__(16) float s_M[5][520];   // persistent M (blocks 0..15)
    __shared__ float st_u[5], st_p[5], st_L[25], st_wr[10], st_ww[5];
    __shared__ float s_red[8][20];
    __shared__ float s_rb[2], s_wb, s_fg[2], s_ga, s_gw, s_pi[2][3];
    __shared__ float s_wrold[2][5], s_uu[5], s_a[5], s_wwn[5];
    __shared__ float s_pold[5], s_Lnew[25];
    __shared__ float s_zw[5], s_z[2][5], s_fw[2][5], s_bw[2][5];
    __shared__ float s_dotA[11], s_dotB[17], s_wrnew[2][5];

    // ---- init persistent LDS state ----
    if (tid < 64) c_s[tid] = 0.f;
    if (bi < 16) {
        for (int i = tid; i < 5 * 520; i += 512) (&s_M[0][0])[i] = 0.f;
        if (tid < 5)  { st_u[tid] = 0.f; st_p[tid] = 0.f; st_ww[tid] = 0.f; }
        if (tid < 25) st_L[tid] = 0.f;
        if (tid < 10) st_wr[tid] = 0.f;
    }
    __syncthreads();

    unsigned gen = 0;

#pragma unroll 1
    for (int t = 0; t < 128; t++) {
        const float* h_in  = hbuf + (t & 1) * 8192;
        float*       h_out = hbuf + ((t + 1) & 1) * 8192;

        // ================= phase G: gates + LSTM update =================
        // prefetch gx for the combine stage (cached, L2-hot)
        float gxv = 0.f;
        if (tid < 256) {
            int c = tid & 15, b = tid >> 4;
            int cgc = (c >> 2) * 512 + bi * 4 + (c & 3);
            gxv = gx[((size_t)t * 16 + b) * 2048 + cgc];
        }

        // ---- single-event staging of full xin (16 x 1536) ----
        {
            const int b5 = tid >> 5, sg = tid & 31;
            const float* ph = h_in + b5 * 512 + sg * 4;
            const float* pr = rbuf + b5 * 1024 + sg * 4;
            f32x4 d0, d1, d2, d3, d4, d5, d6, d7, d8, d9, d10, d11;
            stage12(d0, d1, d2, d3, d4, d5, d6, d7, d8, d9, d10, d11, ph, pr);
#define STW(i, D) { int k = sg * 4 + (i) * 128; int cc = k / 48; \
                    *(f32x4*)&big_u[b5 * 1664 + cc * 52 + (k - cc * 48)] = D; }
            STW(0, d0)  STW(1, d1)  STW(2, d2)  STW(3, d3)
            STW(4, d4)  STW(5, d5)  STW(6, d6)  STW(7, d7)
            STW(8, d8)  STW(9, d9)  STW(10, d10) STW(11, d11)
#undef STW
        }
        __syncthreads();

        // ---- compute: stream weights (cached f32x4) x LDS xin ----
        const int cG  = tid & 15;          // col: gate=cG>>2, jl=cG&3
        const int ksG = tid >> 4;          // 0..31 k-chunk of 48
        const int cg  = (cG >> 2) * 512 + bi * 4 + (cG & 3);
        float acc[16];
#pragma unroll
        for (int b = 0; b < 16; b++) acc[b] = 0.f;
#pragma unroll
        for (int i = 0; i < 12; i++) {
            int kg = ksG * 48 + i * 4;
            const float* wp = (kg < 512) ? W_hh + (size_t)cg * 512 + kg
                                         : W_ih + (size_t)cg * 1536 + kg;
            f32x4 wv = *(const f32x4*)wp;
#pragma unroll
            for (int b = 0; b < 16; b++) {
                f32x4 xv = *(const f32x4*)&big_u[b * 1664 + ksG * 52 + i * 4];
                acc[b] = fmaf(wv[0], xv[0], acc[b]);
                acc[b] = fmaf(wv[1], xv[1], acc[b]);
                acc[b] = fmaf(wv[2], xv[2], acc[b]);
                acc[b] = fmaf(wv[3], xv[3], acc[b]);
            }
        }
        // reduce over ksG: lanes 16,32 in-wave; 8 waves via LDS
#pragma unroll
        for (int b = 0; b < 16; b++) {
            float x = acc[b];
            x += __shfl_xor(x, 16, 64);
            x += __shfl_xor(x, 32, 64);
            acc[b] = x;
        }
        {
            int wv = tid >> 6;
            if ((tid & 63) < 16) {
#pragma unroll
                for (int b = 0; b < 16; b++)
                    s_part[(wv * 16 + cG) * 16 + b] = acc[b];
            }
        }
        __syncthreads();
        if (tid < 256) {
            int c = tid & 15, b = tid >> 4;
            float tot = gxv;
#pragma unroll
            for (int w = 0; w < 8; w++) tot += s_part[(w * 16 + c) * 16 + b];
            s_tot[c * 16 + b] = tot;
        }
        __syncthreads();
        if (tid < 64) {
            int jl = tid & 3, b = tid >> 2;
            float gi  = s_tot[(0 * 4 + jl) * 16 + b];
            float gf  = s_tot[(1 * 4 + jl) * 16 + b];
            float gg  = s_tot[(2 * 4 + jl) * 16 + b];
            float go_ = s_tot[(3 * 4 + jl) * 16 + b];
            float cc = sigmf(gf) * c_s[jl * 16 + b] + sigmf(gi) * tanhf(gg);
            float hh = sigmf(go_) * tanhf(cc);
            c_s[jl * 16 + b] = cc;
            int j = bi * 4 + jl;
            gst(h_out + b * 512 + j, hh);               // coherent
            hr[((size_t)t * 16 + b) * 1536 + j] = hh;   // cached sink
            if (t == 127) {
                out[1048576 + b * 512 + j] = hh;
                out[1048576 + 8192 + b * 512 + j] = cc;
            }
        }
        gen++;
        gsync(flags, gen, bi, tid);

        // ================= phase X: xi = h @ W_int + b_int =================
        {
            // stage h_out (16x512) coherently, chunk-36 rows (conflict-free)
            {
                const int b5 = tid >> 5, s = tid & 31;
                const float* ph = h_out + b5 * 512 + s * 4;
                f32x4 e0, e1, e2, e3;
                cld4o(e0, e1, e2, e3, ph);
#define STX(j, E) { int k = s * 4 + (j) * 128; \
                    *(f32x4*)&big_u[b5 * 576 + (k >> 5) * 36 + (k & 31)] = E; }
                STX(0, e0) STX(1, e1) STX(2, e2) STX(3, e3)
#undef STX
            }
            __syncthreads();
            const int ql  = tid & 15;
            const int kcl = tid >> 4;      // 0..31, chunk of 16 k
#pragma unroll 1
            for (int p = 0; p < 2; p++) {
                if (p == 1 && bi < 95) break;   // pass 2 on blocks 95..127 only
                int q0 = (p == 0) ? bi * 16 : 2048 + (bi - 95) * 16;
                int q  = q0 + ql;
                int qc = (q < 2573) ? q : 2572;
                float wxr[16];
#pragma unroll
                for (int i = 0; i < 16; i++)
                    wxr[i] = W_int[(size_t)(kcl * 16 + i) * 2573 + qc];
                float ax[16];
#pragma unroll
                for (int b = 0; b < 16; b++) ax[b] = 0.f;
#pragma unroll
                for (int b = 0; b < 16; b++) {
                    const f32x4* hp = (const f32x4*)
                        &big_u[b * 576 + (kcl >> 1) * 36 + (kcl & 1) * 16];
#pragma unroll
                    for (int i4 = 0; i4 < 4; i4++) {
                        f32x4 hv = hp[i4];
                        ax[b] = fmaf(wxr[i4 * 4 + 0], hv[0], ax[b]);
                        ax[b] = fmaf(wxr[i4 * 4 + 1], hv[1], ax[b]);
                        ax[b] = fmaf(wxr[i4 * 4 + 2], hv[2], ax[b]);
                        ax[b] = fmaf(wxr[i4 * 4 + 3], hv[3], ax[b]);
                    }
                }
#pragma unroll
                for (int b = 0; b < 16; b++) {
                    float x = ax[b];
                    x += __shfl_xor(x, 16, 64);
                    x += __shfl_xor(x, 32, 64);
                    ax[b] = x;
                }
                {
                    int wv = tid >> 6;
                    if ((tid & 63) < 16) {
#pragma unroll
                        for (int b = 0; b < 16; b++)
                            s_part[(wv * 16 + ql) * 16 + b] = ax[b];
                    }
                }
                __syncthreads();
                if (tid < 256) {
                    int q_l = tid >> 4, b = tid & 15;
                    int qq = q0 + q_l;
                    if (qq < 2573) {
                        float v = b_int[qq];
#pragma unroll
                        for (int w = 0; w < 8; w++)
                            v += s_part[(w * 16 + q_l) * 16 + b];
                        gst(&xib[b * 3072 + qq], v);    // coherent
                    }
                }
                __syncthreads();
            }
        }
        gen++;
        gsync(flags, gen, bi, tid);

        // ================= phase M: memory machinery (blocks 0..15) =================
        if (bi < 16) {
            // stage this batch's xi coherently into big_u (768 f32x4)
            {
                const float* xs = xib + bi * 3072;
                if (tid < 384) {
                    f32x4 d0, d1;
                    cld2(d0, d1, xs + tid * 4, xs + (384 + tid) * 4);
                    *(f32x4*)&big_u[tid * 4]         = d0;
                    *(f32x4*)&big_u[(384 + tid) * 4] = d1;
                }
            }
            __syncthreads();
            const float* xb = big_u;   // staged xi in LDS

            if (tid == 0) {
                s_wb = oneplusf(xb[1538]);
                s_ga = sigmf(xb[2565]);
                s_gw = sigmf(xb[2566]);
            }
            if (tid == 1 || tid == 2) {
                int rr = tid - 1;
                s_rb[rr] = oneplusf(xb[1024 + rr]);
                s_fg[rr] = sigmf(xb[2563 + rr]);
                float z0 = xb[2567 + rr * 3], z1 = xb[2568 + rr * 3], z2 = xb[2569 + rr * 3];
                float mx = fmaxf(z0, fmaxf(z1, z2));
                float e0 = expf(z0 - mx), e1 = expf(z1 - mx), e2 = expf(z2 - mx);
                float s = e0 + e1 + e2;
                s_pi[rr][0] = e0 / s; s_pi[rr][1] = e1 / s; s_pi[rr][2] = e2 / s;
            }
            if (tid >= 32 && tid < 42) { int i = tid - 32; s_wrold[i / 5][i % 5] = st_wr[i]; }
            if (tid >= 64 && tid < 69) { s_pold[tid - 64] = st_p[tid - 64]; }
            __syncthreads();
            if (tid < 5) {
                float psi = (1.f - s_fg[0] * s_wrold[0][tid]) * (1.f - s_fg[1] * s_wrold[1][tid]);
                float un = (st_u[tid] + st_ww[tid] - st_u[tid] * st_ww[tid]) * psi;
                s_uu[tid] = un; st_u[tid] = un;
            }
            __syncthreads();
            if (tid < 5) {
                float excl = 1.f;
#pragma unroll
                for (int m2 = 0; m2 < 5; m2++) {
                    bool before = (s_uu[m2] < s_uu[tid]) || (s_uu[m2] == s_uu[tid] && m2 < tid);
                    if (before) excl *= s_uu[m2];
                }
                s_a[tid] = (1.f - s_uu[tid]) * excl;
            }
            float accA[11];
#pragma unroll
            for (int i = 0; i < 11; i++) accA[i] = 0.f;
            {
                int w = tid;   // 512 threads, 512 w: one element each
                float wk = xb[1026 + w];
                accA[10] += wk * wk;
#pragma unroll
                for (int n = 0; n < 5; n++) {
                    float m_ = s_M[n][w];
                    accA[n]     += m_ * m_;
                    accA[5 + n] += wk * m_;
                }
            }
            blk_reduce<11>(accA, s_red, s_dotA, tid);
            if (tid < 5) {
                float sim = s_dotA[5 + tid] /
                            ((sqrtf(s_dotA[10]) + EPSC) * (sqrtf(s_dotA[tid]) + EPSC));
                s_zw[tid] = s_wb * sim;
            }
            __syncthreads();
            if (tid < 5) {
                float mx = s_zw[0];
#pragma unroll
                for (int m2 = 1; m2 < 5; m2++) mx = fmaxf(mx, s_zw[m2]);
                float sum = 0.f;
#pragma unroll
                for (int m2 = 0; m2 < 5; m2++) sum += expf(s_zw[m2] - mx);
                float cw = expf(s_zw[tid] - mx) / sum;
                float w_ = s_gw * (s_ga * s_a[tid] + (1.f - s_ga) * cw);
                s_wwn[tid] = w_; st_ww[tid] = w_;
            }
            __syncthreads();
            float accB[17];
#pragma unroll
            for (int i = 0; i < 17; i++) accB[i] = 0.f;
            {
                int w = tid;
                float ew = sigmf(xb[1539 + w]);
                float vw = xb[2051 + w];
                float rk0 = xb[w], rk1 = xb[512 + w];
                accB[15] += rk0 * rk0; accB[16] += rk1 * rk1;
#pragma unroll
                for (int n = 0; n < 5; n++) {
                    float m_ = s_M[n][w];
                    float mn_ = m_ * (1.f - s_wwn[n] * ew) + s_wwn[n] * vw;
                    s_M[n][w] = mn_;
                    accB[n]      += mn_ * mn_;
                    accB[5 + n]  += rk0 * mn_;
                    accB[10 + n] += rk1 * mn_;
                }
            }
            blk_reduce<17>(accB, s_red, s_dotB, tid);
            if (tid < 25) {
                int i2 = tid / 5, j2 = tid % 5;
                float Ln = (i2 == j2) ? 0.f
                         : (1.f - s_wwn[i2] - s_wwn[j2]) * st_L[tid] + s_wwn[i2] * s_pold[j2];
                s_Lnew[tid] = Ln; st_L[tid] = Ln;
            }
            __syncthreads();
            if (tid < 5) {
                float wsum = s_wwn[0] + s_wwn[1] + s_wwn[2] + s_wwn[3] + s_wwn[4];
                st_p[tid] = (1.f - wsum) * s_pold[tid] + s_wwn[tid];
            }
            if (tid < 10) {
                int rr = tid / 5, ii = tid % 5;
                float fw = 0.f, bw = 0.f;
#pragma unroll
                for (int j2 = 0; j2 < 5; j2++) {
                    fw += s_Lnew[ii * 5 + j2] * s_wrold[rr][j2];
                    bw += s_Lnew[j2 * 5 + ii] * s_wrold[rr][j2];
                }
                s_fw[rr][ii] = fw; s_bw[rr][ii] = bw;
                float sim = s_dotB[5 + rr * 5 + ii] /
                            ((sqrtf(s_dotB[15 + rr]) + EPSC) * (sqrtf(s_dotB[ii]) + EPSC));
                s_z[rr][ii] = s_rb[rr] * sim;
            }
            __syncthreads();
            if (tid < 10) {
                int rr = tid / 5, ii = tid % 5;
                float mx = s_z[rr][0];
#pragma unroll
                for (int m2 = 1; m2 < 5; m2++) mx = fmaxf(mx, s_z[rr][m2]);
                float sum = 0.f;
#pragma unroll
                for (int m2 = 0; m2 < 5; m2++) sum += expf(s_z[rr][m2] - mx);
                float cr = expf(s_z[rr][ii] - mx) / sum;
                float wn = s_pi[rr][0] * s_bw[rr][ii] + s_pi[rr][1] * cr + s_pi[rr][2] * s_fw[rr][ii];
                s_wrnew[rr][ii] = wn; st_wr[rr * 5 + ii] = wn;
            }
            __syncthreads();
            for (int idx = tid; idx < 1024; idx += 512) {
                int rr = idx >> 9, w = idx & 511;
                float rv = 0.f;
#pragma unroll
                for (int n = 0; n < 5; n++) rv += s_wrnew[rr][n] * s_M[n][w];
                gst(&rbuf[bi * 1024 + idx], rv);        // coherent
                hr[((size_t)t * 16 + bi) * 1536 + 512 + idx] = rv;
            }
        }
        gen++;
        gsync(flags, gen, bi, tid);
    }
}

// ---------------------------------------------------------------------------
// Prologue: gates_x[tok][col] = b_lstm[col] + sum_{k<512} emb[src_tok,k]*W_ih[col,k]
// ---------------------------------------------------------------------------
__global__ __launch_bounds__(256) void k_embgx(
    const int* __restrict__ src, const float* __restrict__ emb,
    const float* __restrict__ W_ih, const float* __restrict__ b_lstm,
    float* __restrict__ gx)
{
    __shared__ __align__(16) float As[16][68];
    __shared__ __align__(16) float Bs[16][68];
    const int tid = threadIdx.x;
    const int bm = blockIdx.x, bn = blockIdx.y;
    const int tm = tid >> 4, tn = tid & 15;
    float acc[4][4] = {};
    for (int k0 = 0; k0 < 512; k0 += 16) {
#pragma unroll
        for (int i = 0; i < 4; i++) {
            int idx = tid + 256 * i;
            int m = idx >> 4, kk = idx & 15;
            int tok = bm * 64 + m;
            int row = src[(tok & 15) * 128 + (tok >> 4)];
            As[kk][m] = emb[(size_t)row * 512 + k0 + kk];
        }
#pragma unroll
        for (int i = 0; i < 4; i++) {
            int idx = tid + 256 * i;
            int n = idx >> 4, kk = idx & 15;
            Bs[kk][n] = W_ih[(size_t)(bn * 64 + n) * 1536 + k0 + kk];
        }
        __syncthreads();
#pragma unroll
        for (int kk = 0; kk < 16; kk++) {
            float4 av = *(const float4*)&As[kk][tm * 4];
            float4 bv = *(const float4*)&Bs[kk][tn * 4];
            float a[4] = {av.x, av.y, av.z, av.w};
            float b[4] = {bv.x, bv.y, bv.z, bv.w};
#pragma unroll
            for (int i = 0; i < 4; i++)
#pragma unroll
                for (int j = 0; j < 4; j++) acc[i][j] = fmaf(a[i], b[j], acc[i][j]);
        }
        __syncthreads();
    }
#pragma unroll
    for (int i = 0; i < 4; i++) {
        int tok = bm * 64 + tm * 4 + i;
#pragma unroll
        for (int j = 0; j < 4; j++) {
            int col = bn * 64 + tn * 4 + j;
            gx[(size_t)tok * 2048 + col] = acc[i][j] + b_lstm[col];
        }
    }
}

// ---------------------------------------------------------------------------
// Epilogue: out[b,s,q] = b_out[q] + sum_k hr[s,b,k]*W_out[k,q]
// ---------------------------------------------------------------------------
__global__ __launch_bounds__(256) void k_out(
    const float* __restrict__ hr, const float* __restrict__ W_out,
    const float* __restrict__ b_out, float* __restrict__ out)
{
    __shared__ __align__(16) float As[16][68];
    __shared__ __align__(16) float Bs[16][68];
    const int tid = threadIdx.x;
    const int bm = blockIdx.x, bn = blockIdx.y;
    const int tm = tid >> 4, tn = tid & 15;
    float acc[4][4] = {};
    for (int k0 = 0; k0 < 1536; k0 += 16) {
#pragma unroll
        for (int i = 0; i < 4; i++) {
            int idx = tid + 256 * i;
            int m = idx >> 4, kk = idx & 15;
            As[kk][m] = hr[(size_t)(bm * 64 + m) * 1536 + k0 + kk];
        }
#pragma unroll
        for (int i = 0; i < 4; i++) {
            int idx = tid + 256 * i;
            int kk = idx >> 6, n = idx & 63;
            Bs[kk][n] = W_out[(size_t)(k0 + kk) * 512 + bn * 64 + n];
        }
        __syncthreads();
#pragma unroll
        for (int kk = 0; kk < 16; kk++) {
            float4 av = *(const float4*)&As[kk][tm * 4];
            float4 bv = *(const float4*)&Bs[kk][tn * 4];
            float a[4] = {av.x, av.y, av.z, av.w};
            float b[4] = {bv.x, bv.y, bv.z, bv.w};
#pragma unroll
            for (int i = 0; i < 4; i++)
#pragma unroll
                for (int j = 0; j < 4; j++) acc[i][j] = fmaf(a[i], b[j], acc[i][j]);
        }
        __syncthreads();
    }
#pragma unroll
    for (int i = 0; i < 4; i++) {
        int tok = bm * 64 + tm * 4 + i;
        int b_ = tok & 15, s_ = tok >> 4;
#pragma unroll
        for (int j = 0; j < 4; j++) {
            int qn = bn * 64 + tn * 4 + j;
            out[(size_t)((b_ << 7) + s_) * 512 + qn] = acc[i][j] + b_out[qn];
        }
    }
}

extern "C" void kernel_launch(void* const* d_in, const int* in_sizes, int n_in,
                              void* d_out, int out_size, void* d_ws, size_t ws_size,
                              hipStream_t stream)
{
    const int*   src    = (const int*)d_in[0];
    const float* emb    = (const float*)d_in[2];
    const float* W_ih   = (const float*)d_in[3];
    const float* W_hh   = (const float*)d_in[4];
    const float* b_lstm = (const float*)d_in[5];
    const float* W_int  = (const float*)d_in[6];
    const float* b_int  = (const float*)d_in[7];
    const float* W_out  = (const float*)d_in[8];
    const float* b_out  = (const float*)d_in[9];

    float* ws  = (float*)d_ws;
    float* out = (float*)d_out;

    float*    hbuf  = ws + OFF_H;
    float*    rbuf  = ws + OFF_R;
    unsigned* flags = (unsigned*)(ws + OFF_FLAGS);
    float*    xib   = ws + OFF_XI;
    float*    gx    = ws + OFF_GX;
    float*    hrb   = ws + OFF_HR;

    // zero recurrent state + sync flags (deterministic across replays)
    hipMemsetAsync(ws, 0, STATE_END * sizeof(float), stream);

    // prologue: token-parallel x-part of gates (+ bias)
    k_embgx<<<dim3(32, 32), 256, 0, stream>>>(src, emb, W_ih, b_lstm, gx);

    // main sequential loop: one persistent kernel (128 blocks x 512 threads,
    // trivially co-resident on 256 CUs; LDS 125KB -> 1 block/CU).
    k_main<<<dim3(NBLK), dim3(512), 0, stream>>>(
        W_ih, W_hh, W_int, b_int, gx, hbuf, rbuf, xib, hrb, out, flags);

    // epilogue: token-parallel output projection
    k_out<<<dim3(32, 8), 256, 0, stream>>>(hrb, W_out, b_out, out);
}

// Round 9
// 4621.634 us; speedup vs baseline: 1.4374x; 1.4374x over previous
//
#include <hip/hip_runtime.h>
#include <math.h>

// B=16, S=128, H=512, V=50000, N=5, R=2, Wd=512, XI=2573
#define EPSC 1e-6f
#define NBLK 128

// ws layout (float offsets)
#define OFF_H     0u         // hbuf[2][16][512]
#define OFF_R     16384u     // r[16][1024]
#define OFF_FLAGS 32768u     // arrival flags: 128 x 32 u32
#define OFF_GO    36864u     // go lines:      128 x 32 u32
#define OFF_XF    40960u     // xi-producer flags: 128 x 32 u32
#define STATE_END 45056u
#define OFF_XI    45056u     // xi[16][3072] (padded rows)
#define OFF_GX    94208u     // gates_x[128][16][2048]
#define OFF_HR    4288512u   // hr[128][16][1536]
// end 7434240 floats = 29.7 MB

typedef float f32x4 __attribute__((ext_vector_type(4)));

__device__ __forceinline__ float sigmf(float x) { return 1.0f / (1.0f + expf(-x)); }
__device__ __forceinline__ float oneplusf(float x) {
    return 1.0f + fmaxf(x, 0.0f) + log1pf(expf(-fabsf(x)));
}

// coherent scalar store (agent scope, bypasses L1/L2) — proven r3-r8
__device__ __forceinline__ void gst(float* p, float v) {
    __hip_atomic_store((unsigned*)p, __float_as_uint(v),
                       __ATOMIC_RELAXED, __HIP_MEMORY_SCOPE_AGENT);
}

// 8 coherent dwordx4 loads, one base, offsets 0..1792 step 256 B. NO waitcnt.
__device__ __forceinline__ void ld8_nw(
    f32x4& d0, f32x4& d1, f32x4& d2, f32x4& d3,
    f32x4& d4, f32x4& d5, f32x4& d6, f32x4& d7, const float* p)
{
    asm volatile(
        "global_load_dwordx4 %0, %8, off sc0 sc1\n\t"
        "global_load_dwordx4 %1, %8, off offset:256 sc0 sc1\n\t"
        "global_load_dwordx4 %2, %8, off offset:512 sc0 sc1\n\t"
        "global_load_dwordx4 %3, %8, off offset:768 sc0 sc1\n\t"
        "global_load_dwordx4 %4, %8, off offset:1024 sc0 sc1\n\t"
        "global_load_dwordx4 %5, %8, off offset:1280 sc0 sc1\n\t"
        "global_load_dwordx4 %6, %8, off offset:1536 sc0 sc1\n\t"
        "global_load_dwordx4 %7, %8, off offset:1792 sc0 sc1"
        : "=&v"(d0), "=&v"(d1), "=&v"(d2), "=&v"(d3),
          "=&v"(d4), "=&v"(d5), "=&v"(d6), "=&v"(d7)
        : "v"(p)
        : "memory");
}

// 16 coherent dwordx4 loads, one base, offsets 0..3840, then waitcnt vmcnt(0).
__device__ __forceinline__ void ld16_w(
    f32x4& d0, f32x4& d1, f32x4& d2, f32x4& d3,
    f32x4& d4, f32x4& d5, f32x4& d6, f32x4& d7,
    f32x4& d8, f32x4& d9, f32x4& d10, f32x4& d11,
    f32x4& d12, f32x4& d13, f32x4& d14, f32x4& d15, const float* p)
{
    asm volatile(
        "global_load_dwordx4 %0, %16, off sc0 sc1\n\t"
        "global_load_dwordx4 %1, %16, off offset:256 sc0 sc1\n\t"
        "global_load_dwordx4 %2, %16, off offset:512 sc0 sc1\n\t"
        "global_load_dwordx4 %3, %16, off offset:768 sc0 sc1\n\t"
        "global_load_dwordx4 %4, %16, off offset:1024 sc0 sc1\n\t"
        "global_load_dwordx4 %5, %16, off offset:1280 sc0 sc1\n\t"
        "global_load_dwordx4 %6, %16, off offset:1536 sc0 sc1\n\t"
        "global_load_dwordx4 %7, %16, off offset:1792 sc0 sc1\n\t"
        "global_load_dwordx4 %8, %16, off offset:2048 sc0 sc1\n\t"
        "global_load_dwordx4 %9, %16, off offset:2304 sc0 sc1\n\t"
        "global_load_dwordx4 %10, %16, off offset:2560 sc0 sc1\n\t"
        "global_load_dwordx4 %11, %16, off offset:2816 sc0 sc1\n\t"
        "global_load_dwordx4 %12, %16, off offset:3072 sc0 sc1\n\t"
        "global_load_dwordx4 %13, %16, off offset:3328 sc0 sc1\n\t"
        "global_load_dwordx4 %14, %16, off offset:3584 sc0 sc1\n\t"
        "global_load_dwordx4 %15, %16, off offset:3840 sc0 sc1\n\t"
        "s_waitcnt vmcnt(0)"
        : "=&v"(d0), "=&v"(d1), "=&v"(d2), "=&v"(d3),
          "=&v"(d4), "=&v"(d5), "=&v"(d6), "=&v"(d7),
          "=&v"(d8), "=&v"(d9), "=&v"(d10), "=&v"(d11),
          "=&v"(d12), "=&v"(d13), "=&v"(d14), "=&v"(d15)
        : "v"(p)
        : "memory");
}

// 8 coherent dwordx4 loads + waitcnt (X staging).
__device__ __forceinline__ void ld8_w(
    f32x4& d0, f32x4& d1, f32x4& d2, f32x4& d3,
    f32x4& d4, f32x4& d5, f32x4& d6, f32x4& d7, const float* p)
{
    asm volatile(
        "global_load_dwordx4 %0, %8, off sc0 sc1\n\t"
        "global_load_dwordx4 %1, %8, off offset:256 sc0 sc1\n\t"
        "global_load_dwordx4 %2, %8, off offset:512 sc0 sc1\n\t"
        "global_load_dwordx4 %3, %8, off offset:768 sc0 sc1\n\t"
        "global_load_dwordx4 %4, %8, off offset:1024 sc0 sc1\n\t"
        "global_load_dwordx4 %5, %8, off offset:1280 sc0 sc1\n\t"
        "global_load_dwordx4 %6, %8, off offset:1536 sc0 sc1\n\t"
        "global_load_dwordx4 %7, %8, off offset:1792 sc0 sc1\n\t"
        "s_waitcnt vmcnt(0)"
        : "=&v"(d0), "=&v"(d1), "=&v"(d2), "=&v"(d3),
          "=&v"(d4), "=&v"(d5), "=&v"(d6), "=&v"(d7)
        : "v"(p)
        : "memory");
}

__device__ __forceinline__ void cld3(
    f32x4& d0, f32x4& d1, f32x4& d2,
    const float* p0, const float* p1, const float* p2)
{
    asm volatile(
        "global_load_dwordx4 %0, %3, off sc0 sc1\n\t"
        "global_load_dwordx4 %1, %4, off sc0 sc1\n\t"
        "global_load_dwordx4 %2, %5, off sc0 sc1\n\t"
        "s_waitcnt vmcnt(0)"
        : "=&v"(d0), "=&v"(d1), "=&v"(d2)
        : "v"(p0), "v"(p1), "v"(p2)
        : "memory");
}

// Fence-free 2-hop mailbox grid barrier (r7-proven: 1 poller per line).
__device__ __forceinline__ void gsync(unsigned* flags, unsigned* go, unsigned gen,
                                      int bi, int tid)
{
    __builtin_amdgcn_s_waitcnt(0);   // drain this wave's payload stores
    __syncthreads();
    if (tid == 0)
        __hip_atomic_store(&flags[bi * 32], gen, __ATOMIC_RELAXED, __HIP_MEMORY_SCOPE_AGENT);
    if (bi == 0) {
        if (tid < NBLK) {
            unsigned v;
            do {
                v = __hip_atomic_load(&flags[tid * 32], __ATOMIC_RELAXED, __HIP_MEMORY_SCOPE_AGENT);
                if (v < gen) __builtin_amdgcn_s_sleep(1);
            } while (v < gen);
        }
        __syncthreads();
        if (tid < NBLK)
            __hip_atomic_store(&go[tid * 32], gen, __ATOMIC_RELAXED, __HIP_MEMORY_SCOPE_AGENT);
    }
    if (tid == 0) {
        unsigned v;
        do {
            v = __hip_atomic_load(&go[bi * 32], __ATOMIC_RELAXED, __HIP_MEMORY_SCOPE_AGENT);
            if (v < gen) __builtin_amdgcn_s_sleep(1);
        } while (v < gen);
    }
    __syncthreads();
}

template <int K>
__device__ __forceinline__ void blk_reduce(float* v, float (*s_red)[20],
                                           float* outp, int tid)
{
#pragma unroll
    for (int i = 0; i < K; i++) {
        float x = v[i];
        for (int o = 32; o > 0; o >>= 1) x += __shfl_down(x, o, 64);
        if ((tid & 63) == 0) s_red[tid >> 6][i] = x;
    }
    __syncthreads();
    if (tid < K) outp[tid] = s_red[0][tid] + s_red[1][tid] + s_red[2][tid] + s_red[3][tid];
    __syncthreads();
}

// ---------------------------------------------------------------------------
// Persistent kernel: all 128 DNC steps. 128 blocks x 256 threads.
// ---------------------------------------------------------------------------
__global__ __launch_bounds__(256, 1) void k_main(
    const float* __restrict__ W_ih, const float* __restrict__ W_hh,
    const float* __restrict__ W_int, const float* __restrict__ b_int,
    const float* __restrict__ gx, float* __restrict__ hbuf,
    float* __restrict__ rbuf, float* __restrict__ xib,
    float* __restrict__ hr, float* __restrict__ out,
    unsigned* __restrict__ flags, unsigned* __restrict__ go,
    unsigned* __restrict__ xf)
{
    const int tid = threadIdx.x;
    const int bi  = blockIdx.x;

    // ---- LDS (~122 KB) ----
    // G: 16 rows x 1688 (chunk-52, row pad -> banks differ per row)
    // X: 16 rows x 592 (chunk-36)   M: xi[3072]
    __shared__ __align__(16) float big_u[27008];
    __shared__ float s_part[1024];
    __shared__ float s_tot[256];
    __shared__ float c_s[64];                     // persistent c (4 j x 16 b)
    __shared__ __align__(16) float s_M[5][520];   // persistent M (blocks 0..15)
    __shared__ float st_u[5], st_p[5], st_L[25], st_wr[10], st_ww[5];
    __shared__ float s_red[4][20];
    __shared__ float s_rb[2], s_wb, s_fg[2], s_ga, s_gw, s_pi[2][3];
    __shared__ float s_wrold[2][5], s_uu[5], s_a[5], s_wwn[5];
    __shared__ float s_pold[5], s_Lnew[25];
    __shared__ float s_zw[5], s_z[2][5], s_fw[2][5], s_bw[2][5];
    __shared__ float s_dotA[11], s_dotB[17], s_wrnew[2][5];

    // ---- init persistent LDS state ----
    if (tid < 64) c_s[tid] = 0.f;
    if (bi < 16) {
        for (int i = tid; i < 5 * 520; i += 256) (&s_M[0][0])[i] = 0.f;
        if (tid < 5)  { st_u[tid] = 0.f; st_p[tid] = 0.f; st_ww[tid] = 0.f; }
        if (tid < 25) st_L[tid] = 0.f;
        if (tid < 10) st_wr[tid] = 0.f;
    }
    __syncthreads();

    unsigned gen = 0;

#pragma unroll 1
    for (int t = 0; t < 128; t++) {
        const float* h_in  = hbuf + (t & 1) * 8192;
        float*       h_out = hbuf + ((t + 1) & 1) * 8192;

        // ================= phase G: gates + LSTM update =================
        // prefetch gx for the combine stage (cached, L2-hot)
        float gxv;
        {
            int c = tid & 15, b = tid >> 4;
            int cgc = (c >> 2) * 512 + bi * 4 + (c & 3);
            gxv = gx[((size_t)t * 16 + b) * 2048 + cgc];
        }

        // ---- single-event staging of full xin (16 x 1536), chunk-52 ----
        {
            const int b = tid >> 4, sg = tid & 15;
            const float* ph = h_in + b * 512 + sg * 4;
            const float* pr = rbuf + b * 1024 + sg * 4;
            f32x4 h0, h1, h2, h3, h4, h5, h6, h7;
            f32x4 r0, r1, r2, r3, r4, r5, r6, r7, r8, r9, r10, r11, r12, r13, r14, r15;
            ld8_nw(h0, h1, h2, h3, h4, h5, h6, h7, ph);
            ld16_w(r0, r1, r2, r3, r4, r5, r6, r7,
                   r8, r9, r10, r11, r12, r13, r14, r15, pr);
#define STG(kk, D) { int k = (kk); int cc = k / 48; \
                     *(f32x4*)&big_u[b * 1688 + cc * 52 + (k - cc * 48)] = D; }
            STG(sg * 4 + 0 * 64, h0)  STG(sg * 4 + 1 * 64, h1)
            STG(sg * 4 + 2 * 64, h2)  STG(sg * 4 + 3 * 64, h3)
            STG(sg * 4 + 4 * 64, h4)  STG(sg * 4 + 5 * 64, h5)
            STG(sg * 4 + 6 * 64, h6)  STG(sg * 4 + 7 * 64, h7)
            STG(512 + sg * 4 + 0 * 64, r0)   STG(512 + sg * 4 + 1 * 64, r1)
            STG(512 + sg * 4 + 2 * 64, r2)   STG(512 + sg * 4 + 3 * 64, r3)
            STG(512 + sg * 4 + 4 * 64, r4)   STG(512 + sg * 4 + 5 * 64, r5)
            STG(512 + sg * 4 + 6 * 64, r6)   STG(512 + sg * 4 + 7 * 64, r7)
            STG(512 + sg * 4 + 8 * 64, r8)   STG(512 + sg * 4 + 9 * 64, r9)
            STG(512 + sg * 4 + 10 * 64, r10) STG(512 + sg * 4 + 11 * 64, r11)
            STG(512 + sg * 4 + 12 * 64, r12) STG(512 + sg * 4 + 13 * 64, r13)
            STG(512 + sg * 4 + 14 * 64, r14) STG(512 + sg * 4 + 15 * 64, r15)
#undef STG
        }
        __syncthreads();

        // ---- compute: stream weights (cached f32x4) x LDS xin ----
        const int cG  = tid & 15;          // col: gate=cG>>2, jl=cG&3
        const int ksG = tid >> 4;          // 0..15 k-chunk of 96
        const int cg  = (cG >> 2) * 512 + bi * 4 + (cG & 3);
        float acc[16];
#pragma unroll
        for (int b = 0; b < 16; b++) acc[b] = 0.f;
#pragma unroll
        for (int i = 0; i < 24; i++) {
            int kg = ksG * 96 + i * 4;
            const float* wp = (kg < 512) ? W_hh + (size_t)cg * 512 + kg
                                         : W_ih + (size_t)cg * 1536 + kg;
            f32x4 wv = *(const f32x4*)wp;
            int lo = ksG * 104 + ((i < 12) ? i * 4 : 52 + (i - 12) * 4);
#pragma unroll
            for (int b = 0; b < 16; b++) {
                f32x4 xv = *(const f32x4*)&big_u[b * 1688 + lo];
                acc[b] = fmaf(wv[0], xv[0], acc[b]);
                acc[b] = fmaf(wv[1], xv[1], acc[b]);
                acc[b] = fmaf(wv[2], xv[2], acc[b]);
                acc[b] = fmaf(wv[3], xv[3], acc[b]);
            }
        }
        // reduce over ksG: lanes 16,32 in-wave; 4 waves via LDS
#pragma unroll
        for (int b = 0; b < 16; b++) {
            float x = acc[b];
            x += __shfl_xor(x, 16, 64);
            x += __shfl_xor(x, 32, 64);
            acc[b] = x;
        }
        {
            int wv = tid >> 6;
            if ((tid & 63) < 16) {
#pragma unroll
                for (int b = 0; b < 16; b++)
                    s_part[(wv * 16 + cG) * 16 + b] = acc[b];
            }
        }
        __syncthreads();
        {
            int c = tid & 15, b = tid >> 4;
            float tot = gxv;
#pragma unroll
            for (int w = 0; w < 4; w++) tot += s_part[(w * 16 + c) * 16 + b];
            s_tot[c * 16 + b] = tot;
        }
        __syncthreads();
        if (tid < 64) {
            int jl = tid & 3, b = tid >> 2;
            float gi  = s_tot[(0 * 4 + jl) * 16 + b];
            float gf  = s_tot[(1 * 4 + jl) * 16 + b];
            float gg  = s_tot[(2 * 4 + jl) * 16 + b];
            float go_ = s_tot[(3 * 4 + jl) * 16 + b];
            float cc = sigmf(gf) * c_s[jl * 16 + b] + sigmf(gi) * tanhf(gg);
            float hh = sigmf(go_) * tanhf(cc);
            c_s[jl * 16 + b] = cc;
            int j = bi * 4 + jl;
            gst(h_out + b * 512 + j, hh);               // coherent
            hr[((size_t)t * 16 + b) * 1536 + j] = hh;   // cached sink
            if (t == 127) {
                out[1048576 + b * 512 + j] = hh;
                out[1048576 + 8192 + b * 512 + j] = cc;
            }
        }
        gen++;
        gsync(flags, go, gen, bi, tid);

        // ================= phase X: xi = h @ W_int + b_int =================
        {
            // stage h_out (16x512) coherently, chunk-36 rows, pad 592
            {
                const int b = tid >> 4, s = tid & 15;
                const float* ph = h_out + b * 512 + s * 4;
                f32x4 e0, e1, e2, e3, e4, e5, e6, e7;
                ld8_w(e0, e1, e2, e3, e4, e5, e6, e7, ph);
#define STX(j, E) { int k = s * 4 + (j) * 64; \
                    *(f32x4*)&big_u[b * 592 + (k >> 5) * 36 + (k & 31)] = E; }
                STX(0, e0) STX(1, e1) STX(2, e2) STX(3, e3)
                STX(4, e4) STX(5, e5) STX(6, e6) STX(7, e7)
#undef STX
            }
            __syncthreads();
            const int ql  = tid & 15;
            const int kcl = tid >> 4;      // 0..15, 32 k each
#pragma unroll 1
            for (int p = 0; p < 2; p++) {
                if (p == 1 && bi < 95) break;   // pass 2 on blocks 95..127 only
                int q0 = (p == 0) ? bi * 16 : 2048 + (bi - 95) * 16;
                int q  = q0 + ql;
                int qc = (q < 2573) ? q : 2572;
                float wxr[32];
#pragma unroll
                for (int i = 0; i < 32; i++)
                    wxr[i] = W_int[(size_t)(kcl * 32 + i) * 2573 + qc];
                float ax[16];
#pragma unroll
                for (int b = 0; b < 16; b++) ax[b] = 0.f;
#pragma unroll
                for (int b = 0; b < 16; b++) {
                    const f32x4* hp = (const f32x4*)&big_u[b * 592 + kcl * 36];
#pragma unroll
                    for (int i4 = 0; i4 < 8; i4++) {
                        f32x4 hv = hp[i4];
                        ax[b] = fmaf(wxr[i4 * 4 + 0], hv[0], ax[b]);
                        ax[b] = fmaf(wxr[i4 * 4 + 1], hv[1], ax[b]);
                        ax[b] = fmaf(wxr[i4 * 4 + 2], hv[2], ax[b]);
                        ax[b] = fmaf(wxr[i4 * 4 + 3], hv[3], ax[b]);
                    }
                }
#pragma unroll
                for (int b = 0; b < 16; b++) {
                    float x = ax[b];
                    x += __shfl_xor(x, 16, 64);
                    x += __shfl_xor(x, 32, 64);
                    ax[b] = x;
                }
                {
                    int wv = tid >> 6;
                    if ((tid & 63) < 16) {
#pragma unroll
                        for (int b = 0; b < 16; b++)
                            s_part[(wv * 16 + ql) * 16 + b] = ax[b];
                    }
                }
                __syncthreads();
                {
                    int q_l = tid >> 4, b = tid & 15;
                    int qq = q0 + q_l;
                    if (qq < 2573) {
                        float v = b_int[qq];
#pragma unroll
                        for (int w = 0; w < 4; w++)
                            v += s_part[(w * 16 + q_l) * 16 + b];
                        gst(&xib[b * 3072 + qq], v);    // coherent
                    }
                }
                __syncthreads();
            }
        }
        // announce xi completion (producer flag; replaces a full barrier)
        __builtin_amdgcn_s_waitcnt(0);
        __syncthreads();
        if (tid == 0)
            __hip_atomic_store(&xf[bi * 32], (unsigned)(t + 1),
                               __ATOMIC_RELAXED, __HIP_MEMORY_SCOPE_AGENT);

        // ================= phase M: memory machinery (blocks 0..15) =================
        if (bi < 16) {
            // wait for all 128 xi producers (one flag per lane)
            if (tid < 128) {
                unsigned v;
                do {
                    v = __hip_atomic_load(&xf[tid * 32], __ATOMIC_RELAXED,
                                          __HIP_MEMORY_SCOPE_AGENT);
                    if (v < (unsigned)(t + 1)) __builtin_amdgcn_s_sleep(2);
                } while (v < (unsigned)(t + 1));
            }
            __syncthreads();
            // stage this batch's xi coherently into big_u
            {
                const float* xs = xib + bi * 3072;
                f32x4 d0, d1, d2;
                cld3(d0, d1, d2,
                     xs + (tid + 0) * 4, xs + (tid + 256) * 4, xs + (tid + 512) * 4);
                *(f32x4*)&big_u[(tid + 0) * 4]   = d0;
                *(f32x4*)&big_u[(tid + 256) * 4] = d1;
                *(f32x4*)&big_u[(tid + 512) * 4] = d2;
            }
            __syncthreads();
            const float* xb = big_u;   // staged xi in LDS

            if (tid == 0) {
                s_wb = oneplusf(xb[1538]);
                s_ga = sigmf(xb[2565]);
                s_gw = sigmf(xb[2566]);
            }
            if (tid == 1 || tid == 2) {
                int rr = tid - 1;
                s_rb[rr] = oneplusf(xb[1024 + rr]);
                s_fg[rr] = sigmf(xb[2563 + rr]);
                float z0 = xb[2567 + rr * 3], z1 = xb[2568 + rr * 3], z2 = xb[2569 + rr * 3];
                float mx = fmaxf(z0, fmaxf(z1, z2));
                float e0 = expf(z0 - mx), e1 = expf(z1 - mx), e2 = expf(z2 - mx);
                float s = e0 + e1 + e2;
                s_pi[rr][0] = e0 / s; s_pi[rr][1] = e1 / s; s_pi[rr][2] = e2 / s;
            }
            if (tid >= 32 && tid < 42) { int i = tid - 32; s_wrold[i / 5][i % 5] = st_wr[i]; }
            if (tid >= 64 && tid < 69) { s_pold[tid - 64] = st_p[tid - 64]; }
            __syncthreads();
            if (tid < 5) {
                float psi = (1.f - s_fg[0] * s_wrold[0][tid]) * (1.f - s_fg[1] * s_wrold[1][tid]);
                float un = (st_u[tid] + st_ww[tid] - st_u[tid] * st_ww[tid]) * psi;
                s_uu[tid] = un; st_u[tid] = un;
            }
            __syncthreads();
            if (tid < 5) {
                float excl = 1.f;
#pragma unroll
                for (int m2 = 0; m2 < 5; m2++) {
                    bool before = (s_uu[m2] < s_uu[tid]) || (s_uu[m2] == s_uu[tid] && m2 < tid);
                    if (before) excl *= s_uu[m2];
                }
                s_a[tid] = (1.f - s_uu[tid]) * excl;
            }
            float accA[11];
#pragma unroll
            for (int i = 0; i < 11; i++) accA[i] = 0.f;
            for (int w = tid; w < 512; w += 256) {
                float wk = xb[1026 + w];
                accA[10] += wk * wk;
#pragma unroll
                for (int n = 0; n < 5; n++) {
                    float m_ = s_M[n][w];
                    accA[n]     += m_ * m_;
                    accA[5 + n] += wk * m_;
                }
            }
            blk_reduce<11>(accA, s_red, s_dotA, tid);
            if (tid < 5) {
                float sim = s_dotA[5 + tid] /
                            ((sqrtf(s_dotA[10]) + EPSC) * (sqrtf(s_dotA[tid]) + EPSC));
                s_zw[tid] = s_wb * sim;
            }
            __syncthreads();
            if (tid < 5) {
                float mx = s_zw[0];
#pragma unroll
                for (int m2 = 1; m2 < 5; m2++) mx = fmaxf(mx, s_zw[m2]);
                float sum = 0.f;
#pragma unroll
                for (int m2 = 0; m2 < 5; m2++) sum += expf(s_zw[m2] - mx);
                float cw = expf(s_zw[tid] - mx) / sum;
                float w_ = s_gw * (s_ga * s_a[tid] + (1.f - s_ga) * cw);
                s_wwn[tid] = w_; st_ww[tid] = w_;
            }
            __syncthreads();
            float accB[17];
#pragma unroll
            for (int i = 0; i < 17; i++) accB[i] = 0.f;
            for (int w = tid; w < 512; w += 256) {
                float ew = sigmf(xb[1539 + w]);
                float vw = xb[2051 + w];
                float rk0 = xb[w], rk1 = xb[512 + w];
                accB[15] += rk0 * rk0; accB[16] += rk1 * rk1;
#pragma unroll
                for (int n = 0; n < 5; n++) {
                    float m_ = s_M[n][w];
                    float mn_ = m_ * (1.f - s_wwn[n] * ew) + s_wwn[n] * vw;
                    s_M[n][w] = mn_;
                    accB[n]      += mn_ * mn_;
                    accB[5 + n]  += rk0 * mn_;
                    accB[10 + n] += rk1 * mn_;
                }
            }
            blk_reduce<17>(accB, s_red, s_dotB, tid);
            if (tid < 25) {
                int i2 = tid / 5, j2 = tid % 5;
                float Ln = (i2 == j2) ? 0.f
                         : (1.f - s_wwn[i2] - s_wwn[j2]) * st_L[tid] + s_wwn[i2] * s_pold[j2];
                s_Lnew[tid] = Ln; st_L[tid] = Ln;
            }
            __syncthreads();
            if (tid < 5) {
                float wsum = s_wwn[0] + s_wwn[1] + s_wwn[2] + s_wwn[3] + s_wwn[4];
                st_p[tid] = (1.f - wsum) * s_pold[tid] + s_wwn[tid];
            }
            if (tid < 10) {
                int rr = tid / 5, ii = tid % 5;
                float fw = 0.f, bw = 0.f;
#pragma unroll
                for (int j2 = 0; j2 < 5; j2++) {
                    fw += s_Lnew[ii * 5 + j2] * s_wrold[rr][j2];
                    bw += s_Lnew[j2 * 5 + ii] * s_wrold[rr][j2];
                }
                s_fw[rr][ii] = fw; s_bw[rr][ii] = bw;
                float sim = s_dotB[5 + rr * 5 + ii] /
                            ((sqrtf(s_dotB[15 + rr]) + EPSC) * (sqrtf(s_dotB[ii]) + EPSC));
                s_z[rr][ii] = s_rb[rr] * sim;
            }
            __syncthreads();
            if (tid < 10) {
                int rr = tid / 5, ii = tid % 5;
                float mx = s_z[rr][0];
#pragma unroll
                for (int m2 = 1; m2 < 5; m2++) mx = fmaxf(mx, s_z[rr][m2]);
                float sum = 0.f;
#pragma unroll
                for (int m2 = 0; m2 < 5; m2++) sum += expf(s_z[rr][m2] - mx);
                float cr = expf(s_z[rr][ii] - mx) / sum;
                float wn = s_pi[rr][0] * s_bw[rr][ii] + s_pi[rr][1] * cr + s_pi[rr][2] * s_fw[rr][ii];
                s_wrnew[rr][ii] = wn; st_wr[rr * 5 + ii] = wn;
            }
            __syncthreads();
            for (int idx = tid; idx < 1024; idx += 256) {
                int rr = idx >> 9, w = idx & 511;
                float rv = 0.f;
#pragma unroll
                for (int n = 0; n < 5; n++) rv += s_wrnew[rr][n] * s_M[n][w];
                gst(&rbuf[bi * 1024 + idx], rv);        // coherent
                hr[((size_t)t * 16 + bi) * 1536 + 512 + idx] = rv;
            }
        }
        gen++;
        gsync(flags, go, gen, bi, tid);
    }
}

// ---------------------------------------------------------------------------
// Prologue: gates_x[tok][col] = b_lstm[col] + sum_{k<512} emb[src_tok,k]*W_ih[col,k]
// ---------------------------------------------------------------------------
__global__ __launch_bounds__(256) void k_embgx(
    const int* __restrict__ src, const float* __restrict__ emb,
    const float* __restrict__ W_ih, const float* __restrict__ b_lstm,
    float* __restrict__ gx)
{
    __shared__ __align__(16) float As[16][68];
    __shared__ __align__(16) float Bs[16][68];
    const int tid = threadIdx.x;
    const int bm = blockIdx.x, bn = blockIdx.y;
    const int tm = tid >> 4, tn = tid & 15;
    float acc[4][4] = {};
    for (int k0 = 0; k0 < 512; k0 += 16) {
#pragma unroll
        for (int i = 0; i < 4; i++) {
            int idx = tid + 256 * i;
            int m = idx >> 4, kk = idx & 15;
            int tok = bm * 64 + m;
            int row = src[(tok & 15) * 128 + (tok >> 4)];
            As[kk][m] = emb[(size_t)row * 512 + k0 + kk];
        }
#pragma unroll
        for (int i = 0; i < 4; i++) {
            int idx = tid + 256 * i;
            int n = idx >> 4, kk = idx & 15;
            Bs[kk][n] = W_ih[(size_t)(bn * 64 + n) * 1536 + k0 + kk];
        }
        __syncthreads();
#pragma unroll
        for (int kk = 0; kk < 16; kk++) {
            float4 av = *(const float4*)&As[kk][tm * 4];
            float4 bv = *(const float4*)&Bs[kk][tn * 4];
            float a[4] = {av.x, av.y, av.z, av.w};
            float b[4] = {bv.x, bv.y, bv.z, bv.w};
#pragma unroll
            for (int i = 0; i < 4; i++)
#pragma unroll
                for (int j = 0; j < 4; j++) acc[i][j] = fmaf(a[i], b[j], acc[i][j]);
        }
        __syncthreads();
    }
#pragma unroll
    for (int i = 0; i < 4; i++) {
        int tok = bm * 64 + tm * 4 + i;
#pragma unroll
        for (int j = 0; j < 4; j++) {
            int col = bn * 64 + tn * 4 + j;
            gx[(size_t)tok * 2048 + col] = acc[i][j] + b_lstm[col];
        }
    }
}

// ---------------------------------------------------------------------------
// Epilogue: out[b,s,q] = b_out[q] + sum_k hr[s,b,k]*W_out[k,q]
// ---------------------------------------------------------------------------
__global__ __launch_bounds__(256) void k_out(
    const float* __restrict__ hr, const float* __restrict__ W_out,
    const float* __restrict__ b_out, float* __restrict__ out)
{
    __shared__ __align__(16) float As[16][68];
    __shared__ __align__(16) float Bs[16][68];
    const int tid = threadIdx.x;
    const int bm = blockIdx.x, bn = blockIdx.y;
    const int tm = tid >> 4, tn = tid & 15;
    float acc[4][4] = {};
    for (int k0 = 0; k0 < 1536; k0 += 16) {
#pragma unroll
        for (int i = 0; i < 4; i++) {
            int idx = tid + 256 * i;
            int m = idx >> 4, kk = idx & 15;
            As[kk][m] = hr[(size_t)(bm * 64 + m) * 1536 + k0 + kk];
        }
#pragma unroll
        for (int i = 0; i < 4; i++) {
            int idx = tid + 256 * i;
            int kk = idx >> 6, n = idx & 63;
            Bs[kk][n] = W_out[(size_t)(k0 + kk) * 512 + bn * 64 + n];
        }
        __syncthreads();
#pragma unroll
        for (int kk = 0; kk < 16; kk++) {
            float4 av = *(const float4*)&As[kk][tm * 4];
            float4 bv = *(const float4*)&Bs[kk][tn * 4];
            float a[4] = {av.x, av.y, av.z, av.w};
            float b[4] = {bv.x, bv.y, bv.z, bv.w};
#pragma unroll
            for (int i = 0; i < 4; i++)
#pragma unroll
                for (int j = 0; j < 4; j++) acc[i][j] = fmaf(a[i], b[j], acc[i][j]);
        }
        __syncthreads();
    }
#pragma unroll
    for (int i = 0; i < 4; i++) {
        int tok = bm * 64 + tm * 4 + i;
        int b_ = tok & 15, s_ = tok >> 4;
#pragma unroll
        for (int j = 0; j < 4; j++) {
            int qn = bn * 64 + tn * 4 + j;
            out[(size_t)((b_ << 7) + s_) * 512 + qn] = acc[i][j] + b_out[qn];
        }
    }
}

extern "C" void kernel_launch(void* const* d_in, const int* in_sizes, int n_in,
                              void* d_out, int out_size, void* d_ws, size_t ws_size,
                              hipStream_t stream)
{
    const int*   src    = (const int*)d_in[0];
    const float* emb    = (const float*)d_in[2];
    const float* W_ih   = (const float*)d_in[3];
    const float* W_hh   = (const float*)d_in[4];
    const float* b_lstm = (const float*)d_in[5];
    const float* W_int  = (const float*)d_in[6];
    const float* b_int  = (const float*)d_in[7];
    const float* W_out  = (const float*)d_in[8];
    const float* b_out  = (const float*)d_in[9];

    float* ws  = (float*)d_ws;
    float* out = (float*)d_out;

    float*    hbuf  = ws + OFF_H;
    float*    rbuf  = ws + OFF_R;
    unsigned* flags = (unsigned*)(ws + OFF_FLAGS);
    unsigned* go    = (unsigned*)(ws + OFF_GO);
    unsigned* xf    = (unsigned*)(ws + OFF_XF);
    float*    xib   = ws + OFF_XI;
    float*    gx    = ws + OFF_GX;
    float*    hrb   = ws + OFF_HR;

    // zero recurrent state + all sync flags (deterministic across replays)
    hipMemsetAsync(ws, 0, STATE_END * sizeof(float), stream);

    // prologue: token-parallel x-part of gates (+ bias)
    k_embgx<<<dim3(32, 32), 256, 0, stream>>>(src, emb, W_ih, b_lstm, gx);

    // main sequential loop: one persistent kernel (128 blocks x 256 threads)
    k_main<<<dim3(NBLK), dim3(256), 0, stream>>>(
        W_ih, W_hh, W_int, b_int, gx, hbuf, rbuf, xib, hrb, out, flags, go, xf);

    // epilogue: token-parallel output projection
    k_out<<<dim3(32, 8), 256, 0, stream>>>(hrb, W_out, b_out, out);
}